// Round 3
// baseline (1399.072 us; speedup 1.0000x reference)
//
#include <hip/hip_runtime.h>
#include <hip/hip_bf16.h>

#define HID 128
#define SEQ 512
#define INS 14
#define BC 16
#define K0STEPS 5   // K = 160 : [x(14) | 1 | pad->32 | h0(128)]
#define K1STEPS 8   // K = 256 : [h0(128) | h1(128)]
#define X0STRIDE 168  // 160 + 8 pad shorts -> 336B rows, 2-way-bank-free
#define X1STRIDE 264  // 256 + 8 pad shorts -> 528B rows, 2-way-bank-free

typedef __attribute__((ext_vector_type(8))) short bs8;
typedef __attribute__((ext_vector_type(4))) float f4;

__device__ __forceinline__ short f2bf(float f) {
    union { float f; unsigned u; } a; a.f = f;
    unsigned u = a.u;
    u += 0x7fffu + ((u >> 16) & 1u);   // RNE
    return (short)(u >> 16);
}
__device__ __forceinline__ float bf2f(short s) {
    union { unsigned u; float f; } a;
    a.u = ((unsigned)(unsigned short)s) << 16;
    return a.f;
}
__device__ __forceinline__ float sigm(float x) {
    return __builtin_amdgcn_rcpf(1.f + __builtin_amdgcn_exp2f(x * -1.44269504f));
}
__device__ __forceinline__ float tanh_(float x) {
    return __builtin_fmaf(2.f, __builtin_amdgcn_rcpf(1.f + __builtin_amdgcn_exp2f(x * -2.88539008f)), -1.f);
}

// amdgpu_waves_per_eu(2,2): pin the allocator's occupancy TARGET to exactly
// 2 waves/EU -> 256-VGPR budget per wave. __launch_bounds__(512,2) (round 2)
// only set the MINIMUM (a constraint the default already met) and produced a
// byte-identical 128-VGPR binary that spilled all 208 persistent weight regs
// (WRITE_SIZE 92 MB of scratch traffic). 8 waves x 128 blocks = 1 block/CU =
// exactly 2 waves/EU, so this pin costs no real occupancy.
__global__ __attribute__((amdgpu_flat_work_group_size(512, 512)))
__attribute__((amdgpu_waves_per_eu(2, 2))) void lstm_fused(
    const float* __restrict__ x,
    const float* __restrict__ Wih0, const float* __restrict__ Whh0,
    const float* __restrict__ bih0, const float* __restrict__ bhh0,
    const float* __restrict__ Wih1, const float* __restrict__ Whh1,
    const float* __restrict__ bih1, const float* __restrict__ bhh1,
    const float* __restrict__ Wfc,  const float* __restrict__ bfc,
    float* __restrict__ out)
{
    __shared__ __align__(16) short xh0[2][BC][X0STRIDE];
    __shared__ __align__(16) short xh1[2][BC][X1STRIDE];

    const int tid  = threadIdx.x;
    const int lane = tid & 63;
    const int wv   = tid >> 6;      // 0..7
    const int col  = lane & 15;     // n within 16-wide tile
    const int quad = lane >> 4;     // 0..3
    const int u    = wv * 16 + col; // hidden unit 0..127 owned by this lane
    const int b0   = blockIdx.x * BC;

    // ---- persistent weight fragments (VGPR-resident across all 512 steps) ----
    // B-frag layout: B[k = quad*8 + j][n = lane&15]; tile g covers gate rows g*128 + wv*16 + col
    bs8 w0[4][K0STEPS];
    bs8 w1[4][K1STEPS];
    float bias1v[4];
#pragma unroll
    for (int g = 0; g < 4; ++g) {
        const int row = g * HID + u;
#pragma unroll
        for (int ks = 0; ks < K0STEPS; ++ks) {
            bs8 v;
#pragma unroll
            for (int j = 0; j < 8; ++j) {
                int k = ks * 32 + quad * 8 + j;
                float f;
                if (k < INS)        f = Wih0[row * INS + k];
                else if (k == INS)  f = bih0[row] + bhh0[row];   // bias folded via A's "1" column
                else if (k < 32)    f = 0.f;
                else                f = Whh0[row * HID + (k - 32)];
                v[j] = f2bf(f);
            }
            w0[g][ks] = v;
        }
#pragma unroll
        for (int ks = 0; ks < K1STEPS; ++ks) {
            bs8 v;
#pragma unroll
            for (int j = 0; j < 8; ++j) {
                int k = ks * 32 + quad * 8 + j;
                float f = (k < HID) ? Wih1[row * HID + k] : Whh1[row * HID + (k - HID)];
                v[j] = f2bf(f);
            }
            w1[g][ks] = v;
        }
        bias1v[g] = bih1[row] + bhh1[row];
    }

    // ---- LDS init: zeros (h0(-1)=h1(-1)=0, pads) + constant-1 bias column ----
    for (int idx = tid; idx < 2 * BC * X0STRIDE; idx += 512) ((short*)xh0)[idx] = 0;
    for (int idx = tid; idx < 2 * BC * X1STRIDE; idx += 512) ((short*)xh1)[idx] = 0;
    __syncthreads();
    if (tid < 2 * BC) xh0[tid >> 4][tid & 15][INS] = (short)0x3f80;  // 1.0 bf16

    // ---- x(t) staging: one float per thread, prefetched one step ahead ----
    const bool xldr = (tid < BC * INS);          // 224 threads
    const int  xm = tid / INS;
    const int  xi = tid - xm * INS;
    const float* xp = xldr ? (x + ((size_t)(b0 + xm) * SEQ) * INS + xi) : x;
    float xv = xldr ? xp[0] : 0.f;

    float c0[4] = {0.f, 0.f, 0.f, 0.f};
    float c1[4] = {0.f, 0.f, 0.f, 0.f};
    const int aoff = quad * 8;

    for (int t = 0; t < SEQ; ++t) {
        const int p = t & 1, q = p ^ 1;
        if (xldr) xh0[p][xm][xi] = f2bf(xv);
        float xnext = (xldr && (t + 1 < SEQ)) ? xp[(t + 1) * INS] : 0.f;  // hidden across barrier
        __syncthreads();  // B2: x(t) + h0(t-1) [+ h1(t-1)] visible

        // ---- layer 0: gates0 = [x|1|h0] @ W0^T ----
        f4 a0[4] = {{0,0,0,0},{0,0,0,0},{0,0,0,0},{0,0,0,0}};
#pragma unroll
        for (int ks = 0; ks < K0STEPS; ++ks) {
            bs8 af = *(const bs8*)&xh0[p][col][ks * 32 + aoff];
#pragma unroll
            for (int g = 0; g < 4; ++g)
                a0[g] = __builtin_amdgcn_mfma_f32_16x16x32_bf16(af, w0[g][ks], a0[g], 0, 0, 0);
        }
        // ---- cell 0 (fully in-register: i,f,g,o share lane mapping) ----
#pragma unroll
        for (int r = 0; r < 4; ++r) {
            float ig = sigm(a0[0][r]);
            float fg = sigm(a0[1][r]);
            float gg = tanh_(a0[2][r]);
            float og = sigm(a0[3][r]);
            c0[r] = __builtin_fmaf(fg, c0[r], ig * gg);
            float h = og * tanh_(c0[r]);
            short hb = f2bf(h);
            int m = quad * 4 + r;
            xh0[q][m][32 + u] = hb;   // next step's layer-0 A panel
            xh1[p][m][u]      = hb;   // this step's layer-1 A panel
        }
        __syncthreads();  // B1: h0(t) visible for layer 1

        // ---- layer 1: gates1 = [h0(t)|h1(t-1)] @ W1^T + b1 ----
        f4 a1[4];
#pragma unroll
        for (int g = 0; g < 4; ++g) {
            f4 bini;
            bini[0] = bias1v[g]; bini[1] = bias1v[g]; bini[2] = bias1v[g]; bini[3] = bias1v[g];
            a1[g] = bini;
        }
#pragma unroll
        for (int ks = 0; ks < K1STEPS; ++ks) {
            bs8 af = *(const bs8*)&xh1[p][col][ks * 32 + aoff];
#pragma unroll
            for (int g = 0; g < 4; ++g)
                a1[g] = __builtin_amdgcn_mfma_f32_16x16x32_bf16(af, w1[g][ks], a1[g], 0, 0, 0);
        }
        // ---- cell 1 ----
#pragma unroll
        for (int r = 0; r < 4; ++r) {
            float ig = sigm(a1[0][r]);
            float fg = sigm(a1[1][r]);
            float gg = tanh_(a1[2][r]);
            float og = sigm(a1[3][r]);
            c1[r] = __builtin_fmaf(fg, c1[r], ig * gg);
            float h = og * tanh_(c1[r]);
            int m = quad * 4 + r;
            xh1[q][m][HID + u] = f2bf(h);  // next step's layer-1 A panel (h1 half)
        }
        xv = xnext;
        // loop-top barrier doubles as the post-cell1 barrier
    }
    __syncthreads();

    // ---- final FC (128 -> 1) + sigmoid; h1(T-1) sits in xh1[0][.][HID+..] ----
    if (tid < BC) {
        float s = bfc[0];
#pragma unroll 8
        for (int k2 = 0; k2 < HID; ++k2)
            s += bf2f(xh1[0][tid][HID + k2]) * Wfc[k2];
        out[b0 + tid] = sigm(s);
    }
}

extern "C" void kernel_launch(void* const* d_in, const int* in_sizes, int n_in,
                              void* d_out, int out_size, void* d_ws, size_t ws_size,
                              hipStream_t stream) {
    const float* x    = (const float*)d_in[0];
    const float* Wih0 = (const float*)d_in[1];
    const float* Whh0 = (const float*)d_in[2];
    const float* bih0 = (const float*)d_in[3];
    const float* bhh0 = (const float*)d_in[4];
    const float* Wih1 = (const float*)d_in[5];
    const float* Whh1 = (const float*)d_in[6];
    const float* bih1 = (const float*)d_in[7];
    const float* bhh1 = (const float*)d_in[8];
    const float* Wfc  = (const float*)d_in[9];
    const float* bfc  = (const float*)d_in[10];
    float* out = (float*)d_out;

    dim3 grid(2048 / BC);   // 128 blocks, 1 per CU, BC=16 batch rows each
    dim3 block(512);        // 8 waves; each wave owns 16 hidden units (i,f,g,o tiles)
    lstm_fused<<<grid, block, 0, stream>>>(x, Wih0, Whh0, bih0, bhh0,
                                           Wih1, Whh1, bih1, bhh1, Wfc, bfc, out);
}

// Round 4
// 1354.823 us; speedup vs baseline: 1.0327x; 1.0327x over previous
//
#include <hip/hip_runtime.h>
#include <hip/hip_bf16.h>

#define HID 128
#define SEQ 512
#define INS 14
#define BC 16
// K0 = 160 : [x(14) | 1 | pad->32 | h0(128)]   -> 5 k-steps of 32
// K1 = 256 : [h0(128) | h1(128)]               -> 8 k-steps of 32
#define X0STRIDE 168  // 160 + 8 pad shorts
#define X1STRIDE 264  // 256 + 8 pad shorts
#define NFRAG0 10240          // 8 waves * 4 gates * 5 ksteps * 64 lanes
#define NFRAG1 16384          // 8 waves * 4 gates * 8 ksteps * 64 lanes
#define W1BASE (NFRAG0 * 8)   // short offset of W1 region in ws

typedef __attribute__((ext_vector_type(8))) short bs8;
typedef __attribute__((ext_vector_type(4))) float f4;

__device__ __forceinline__ short f2bf(float f) {
    union { float f; unsigned u; } a; a.f = f;
    unsigned u = a.u;
    u += 0x7fffu + ((u >> 16) & 1u);   // RNE
    return (short)(u >> 16);
}
__device__ __forceinline__ float bf2f(short s) {
    union { unsigned u; float f; } a;
    a.u = ((unsigned)(unsigned short)s) << 16;
    return a.f;
}
__device__ __forceinline__ float sigm(float x) {
    return __builtin_amdgcn_rcpf(1.f + __builtin_amdgcn_exp2f(x * -1.44269504f));
}
__device__ __forceinline__ float tanh_(float x) {
    return __builtin_fmaf(2.f, __builtin_amdgcn_rcpf(1.f + __builtin_amdgcn_exp2f(x * -2.88539008f)), -1.f);
}

// ---------------------------------------------------------------------------
// prep: swizzle weights into MFMA B-fragment order in ws (bf16 bits).
// Frag (wv,g,ks,lane) -> ws shorts [fragIdx*8 .. +8), fragIdx linear in
// ((wv*4+g)*KSTEPS+ks)*64+lane. Bias folded into k==14 column of W0.
// ---------------------------------------------------------------------------
__global__ void lstm_prep(
    const float* __restrict__ Wih0, const float* __restrict__ Whh0,
    const float* __restrict__ bih0, const float* __restrict__ bhh0,
    const float* __restrict__ Wih1, const float* __restrict__ Whh1,
    short* __restrict__ wsw)
{
    int f = blockIdx.x * 256 + threadIdx.x;
    if (f >= NFRAG0 + NFRAG1) return;
    if (f < NFRAG0) {
        int lane = f & 63, t = f >> 6;
        int ks = t % 5, gw = t / 5, g = gw & 3, wv = gw >> 2;
        int row = g * HID + wv * 16 + (lane & 15);
        int kbase = ks * 32 + (lane >> 4) * 8;
        for (int j = 0; j < 8; ++j) {
            int k = kbase + j;
            float v;
            if (k < INS)        v = Wih0[row * INS + k];
            else if (k == INS)  v = bih0[row] + bhh0[row];
            else if (k < 32)    v = 0.f;
            else                v = Whh0[row * HID + (k - 32)];
            wsw[f * 8 + j] = f2bf(v);
        }
    } else {
        int fl = f - NFRAG0;
        int lane = fl & 63, t = fl >> 6;
        int ks = t & 7, g = (t >> 3) & 3, wv = t >> 5;
        int row = g * HID + wv * 16 + (lane & 15);
        int kbase = ks * 32 + (lane >> 4) * 8;
        for (int j = 0; j < 8; ++j) {
            int k = kbase + j;
            float v = (k < HID) ? Wih1[row * HID + k] : Whh1[row * HID + (k - HID)];
            wsw[f * 8 + j] = f2bf(v);
        }
    }
}

// ---------------------------------------------------------------------------
// main: fully array-free hot path. 52 named bs8 weight frags (SSA -> VGPRs),
// named f4 accumulators, named float c-state. Rounds 1-3 used local arrays:
// SROA runs before unrolling -> dynamic indices -> allocas stayed in scratch
// (VGPR_Count pinned at 128, WRITE_SIZE 92 MB of scratch churn) regardless of
// occupancy attributes. waves_per_eu(2,2) => 256-VGPR budget, 2 waves/SIMD.
// ---------------------------------------------------------------------------
__global__ __attribute__((amdgpu_flat_work_group_size(512, 512)))
__attribute__((amdgpu_waves_per_eu(2, 2))) void lstm_fused(
    const float* __restrict__ x,
    const float* __restrict__ Wfc,  const float* __restrict__ bfc,
    const float* __restrict__ bih1, const float* __restrict__ bhh1,
    const short* __restrict__ wsw,
    float* __restrict__ out)
{
    __shared__ __align__(16) short xh0[2][BC][X0STRIDE];
    __shared__ __align__(16) short xh1[2][BC][X1STRIDE];

    const int tid  = threadIdx.x;
    const int lane = tid & 63;
    const int wv   = tid >> 6;      // 0..7
    const int col  = lane & 15;
    const int quad = lane >> 4;
    const int u    = wv * 16 + col; // hidden unit owned by this lane
    const int b0   = blockIdx.x * BC;

    // ---- load persistent weight fragments: named SSA values only ----
    const short* wb0 = wsw + ((wv * 20) * 64 + lane) * 8;           // wv*4*5
    const short* wb1 = wsw + W1BASE + ((wv * 32) * 64 + lane) * 8;  // wv*4*8
#define DW0(g,ks) const bs8 w0_##g##_##ks = *(const bs8*)(wb0 + ((g)*5+(ks))*512);
#define DW1(g,ks) const bs8 w1_##g##_##ks = *(const bs8*)(wb1 + ((g)*8+(ks))*512);
    DW0(0,0) DW0(0,1) DW0(0,2) DW0(0,3) DW0(0,4)
    DW0(1,0) DW0(1,1) DW0(1,2) DW0(1,3) DW0(1,4)
    DW0(2,0) DW0(2,1) DW0(2,2) DW0(2,3) DW0(2,4)
    DW0(3,0) DW0(3,1) DW0(3,2) DW0(3,3) DW0(3,4)
    DW1(0,0) DW1(0,1) DW1(0,2) DW1(0,3) DW1(0,4) DW1(0,5) DW1(0,6) DW1(0,7)
    DW1(1,0) DW1(1,1) DW1(1,2) DW1(1,3) DW1(1,4) DW1(1,5) DW1(1,6) DW1(1,7)
    DW1(2,0) DW1(2,1) DW1(2,2) DW1(2,3) DW1(2,4) DW1(2,5) DW1(2,6) DW1(2,7)
    DW1(3,0) DW1(3,1) DW1(3,2) DW1(3,3) DW1(3,4) DW1(3,5) DW1(3,6) DW1(3,7)

    const float b1_0 = bih1[0 * HID + u] + bhh1[0 * HID + u];
    const float b1_1 = bih1[1 * HID + u] + bhh1[1 * HID + u];
    const float b1_2 = bih1[2 * HID + u] + bhh1[2 * HID + u];
    const float b1_3 = bih1[3 * HID + u] + bhh1[3 * HID + u];

    // ---- LDS init: zeros + constant-1 bias column ----
    for (int idx = tid; idx < 2 * BC * X0STRIDE; idx += 512) ((short*)xh0)[idx] = 0;
    for (int idx = tid; idx < 2 * BC * X1STRIDE; idx += 512) ((short*)xh1)[idx] = 0;
    __syncthreads();
    if (tid < 2 * BC) xh0[tid >> 4][tid & 15][INS] = (short)0x3f80;  // 1.0 bf16

    // ---- x(t) staging: one float per thread, prefetched one step ahead ----
    const bool xldr = (tid < BC * INS);          // 224 threads
    const int  xm = tid / INS;
    const int  xi = tid - xm * INS;
    const float* xp = xldr ? (x + ((size_t)(b0 + xm) * SEQ) * INS + xi) : x;
    float xv = xldr ? xp[0] : 0.f;

    float c0_0 = 0.f, c0_1 = 0.f, c0_2 = 0.f, c0_3 = 0.f;
    float c1_0 = 0.f, c1_1 = 0.f, c1_2 = 0.f, c1_3 = 0.f;
    const int aoff = quad * 8;

    for (int t = 0; t < SEQ; ++t) {
        const int p = t & 1, q = p ^ 1;
        if (xldr) xh0[p][xm][xi] = f2bf(xv);
        float xnext = (xldr && (t + 1 < SEQ)) ? xp[(t + 1) * INS] : 0.f;
        __syncthreads();  // x(t) + h0(t-1) + h1(t-1) visible

        // ---- layer 0: gates0 = [x|1|h0] @ W0^T ----
        f4 acc0_0 = {0.f,0.f,0.f,0.f}, acc0_1 = {0.f,0.f,0.f,0.f};
        f4 acc0_2 = {0.f,0.f,0.f,0.f}, acc0_3 = {0.f,0.f,0.f,0.f};
#define L0(ks) { const bs8 af = *(const bs8*)&xh0[p][col][(ks)*32 + aoff]; \
        acc0_0 = __builtin_amdgcn_mfma_f32_16x16x32_bf16(af, w0_0_##ks, acc0_0, 0,0,0); \
        acc0_1 = __builtin_amdgcn_mfma_f32_16x16x32_bf16(af, w0_1_##ks, acc0_1, 0,0,0); \
        acc0_2 = __builtin_amdgcn_mfma_f32_16x16x32_bf16(af, w0_2_##ks, acc0_2, 0,0,0); \
        acc0_3 = __builtin_amdgcn_mfma_f32_16x16x32_bf16(af, w0_3_##ks, acc0_3, 0,0,0); }
        L0(0) L0(1) L0(2) L0(3) L0(4)

        // ---- cell 0: i,f,g,o share the C/D lane mapping -> in-register ----
#define CELL0(r) { \
        float ig = sigm(acc0_0[r]); \
        float fg = sigm(acc0_1[r]); \
        float gg = tanh_(acc0_2[r]); \
        float og = sigm(acc0_3[r]); \
        c0_##r = __builtin_fmaf(fg, c0_##r, ig * gg); \
        float h = og * tanh_(c0_##r); \
        short hb = f2bf(h); \
        xh0[q][quad * 4 + r][32 + u] = hb; \
        xh1[p][quad * 4 + r][u]      = hb; }
        CELL0(0) CELL0(1) CELL0(2) CELL0(3)
        __syncthreads();  // h0(t) visible for layer 1

        // ---- layer 1: gates1 = [h0(t)|h1(t-1)] @ W1^T + b1 ----
        f4 acc1_0 = {b1_0, b1_0, b1_0, b1_0};
        f4 acc1_1 = {b1_1, b1_1, b1_1, b1_1};
        f4 acc1_2 = {b1_2, b1_2, b1_2, b1_2};
        f4 acc1_3 = {b1_3, b1_3, b1_3, b1_3};
#define L1(ks) { const bs8 af = *(const bs8*)&xh1[p][col][(ks)*32 + aoff]; \
        acc1_0 = __builtin_amdgcn_mfma_f32_16x16x32_bf16(af, w1_0_##ks, acc1_0, 0,0,0); \
        acc1_1 = __builtin_amdgcn_mfma_f32_16x16x32_bf16(af, w1_1_##ks, acc1_1, 0,0,0); \
        acc1_2 = __builtin_amdgcn_mfma_f32_16x16x32_bf16(af, w1_2_##ks, acc1_2, 0,0,0); \
        acc1_3 = __builtin_amdgcn_mfma_f32_16x16x32_bf16(af, w1_3_##ks, acc1_3, 0,0,0); }
        L1(0) L1(1) L1(2) L1(3) L1(4) L1(5) L1(6) L1(7)

#define CELL1(r) { \
        float ig = sigm(acc1_0[r]); \
        float fg = sigm(acc1_1[r]); \
        float gg = tanh_(acc1_2[r]); \
        float og = sigm(acc1_3[r]); \
        c1_##r = __builtin_fmaf(fg, c1_##r, ig * gg); \
        float h = og * tanh_(c1_##r); \
        xh1[q][quad * 4 + r][HID + u] = f2bf(h); }
        CELL1(0) CELL1(1) CELL1(2) CELL1(3)

        xv = xnext;
        // loop-top barrier doubles as the post-cell1 barrier
    }
    __syncthreads();

    // ---- final FC (128 -> 1) + sigmoid; h1(T-1) in xh1[0][.][HID+..] ----
    if (tid < BC) {
        float s = bfc[0];
#pragma unroll 8
        for (int k2 = 0; k2 < HID; ++k2)
            s += bf2f(xh1[0][tid][HID + k2]) * Wfc[k2];
        out[b0 + tid] = sigm(s);
    }
}

extern "C" void kernel_launch(void* const* d_in, const int* in_sizes, int n_in,
                              void* d_out, int out_size, void* d_ws, size_t ws_size,
                              hipStream_t stream) {
    const float* x    = (const float*)d_in[0];
    const float* Wih0 = (const float*)d_in[1];
    const float* Whh0 = (const float*)d_in[2];
    const float* bih0 = (const float*)d_in[3];
    const float* bhh0 = (const float*)d_in[4];
    const float* Wih1 = (const float*)d_in[5];
    const float* Whh1 = (const float*)d_in[6];
    const float* bih1 = (const float*)d_in[7];
    const float* bhh1 = (const float*)d_in[8];
    const float* Wfc  = (const float*)d_in[9];
    const float* bfc  = (const float*)d_in[10];
    float* out = (float*)d_out;
    short* wsw = (short*)d_ws;   // 426 KB of bf16 fragment-ordered weights

    int nfrag = NFRAG0 + NFRAG1;
    lstm_prep<<<(nfrag + 255) / 256, 256, 0, stream>>>(Wih0, Whh0, bih0, bhh0,
                                                       Wih1, Whh1, wsw);
    dim3 grid(2048 / BC);   // 128 blocks, 1 per CU
    dim3 block(512);        // 8 waves; each wave owns 16 hidden units
    lstm_fused<<<grid, block, 0, stream>>>(x, Wfc, bfc, bih1, bhh1, wsw, out);
}